// Round 4
// baseline (232.093 us; speedup 1.0000x reference)
//
#include <hip/hip_runtime.h>

typedef short bf16x8 __attribute__((ext_vector_type(8)));
typedef float f32x4  __attribute__((ext_vector_type(4)));

__device__ __forceinline__ unsigned short f32_to_bf16(float f) {
  union { float f; unsigned int u; } v; v.f = f;
  unsigned int u = v.u;
  u += 0x7fffu + ((u >> 16) & 1u);   // round-to-nearest-even
  return (unsigned short)(u >> 16);
}
__device__ __forceinline__ float bf16lo_to_f32(unsigned int u) {
  union { unsigned int u; float f; } v; v.u = u << 16; return v.f;
}
__device__ __forceinline__ float bf16hi_to_f32(unsigned int u) {
  union { unsigned int u; float f; } v; v.u = u & 0xffff0000u; return v.f;
}

// LDS row stride 40 ushorts (80 B = 20 banks): fragment rows land 20 banks
// apart -> worst 2-way aliasing (free per m136); 80B keeps 16B alignment.
#define LDSTRIDE 40

// h = x @ W.T + b, h[0,:]=0, stored bf16.
// Tile: BM=128 atoms x BN=128 cols, 256 threads (4 waves).
__global__ __launch_bounds__(256, 2) void gin_gemm(
    const float* __restrict__ x, const float* __restrict__ W,
    const float* __restrict__ bias, unsigned short* __restrict__ h, int M) {
  __shared__ __align__(16) unsigned short Xs[128 * LDSTRIDE];  // 10.2 KB
  __shared__ __align__(16) unsigned short Ws[128 * LDSTRIDE];  // 10.2 KB

  const int tid  = threadIdx.x;
  const int wid  = tid >> 6;
  const int lane = tid & 63;
  const int row0  = blockIdx.x * 128;   // atom tile
  const int ncol0 = blockIdx.y * 128;   // col tile

  f32x4 acc[2][8] = {};  // [ng][ag]

  const int srow = tid >> 2;           // 0..63
  const int sk0  = (tid & 3) << 3;     // 0,8,16,24
  int ar0 = row0 + srow;        if (ar0 >= M) ar0 = M - 1;
  int ar1 = row0 + 64 + srow;   if (ar1 >= M) ar1 = M - 1;
  const float* aRow0 = x + (size_t)ar0 * 256 + sk0;
  const float* aRow1 = x + (size_t)ar1 * 256 + sk0;
  const float* bRow0 = W + (size_t)(ncol0 + srow) * 256 + sk0;
  const float* bRow1 = W + (size_t)(ncol0 + 64 + srow) * 256 + sk0;

  const int quad = lane >> 4;
  const int c16  = lane & 15;
  float4 biasv[2];
#pragma unroll
  for (int ng = 0; ng < 2; ++ng)
    biasv[ng] = *(const float4*)(bias + ncol0 + wid * 32 + ng * 16 + quad * 4);

  for (int kt = 0; kt < 8; ++kt) {
    const int kb = kt * 32;
#pragma unroll
    for (int p = 0; p < 2; ++p) {  // stage x rows
      const float* src = p ? aRow1 : aRow0;
      float4 v0 = *(const float4*)(src + kb);
      float4 v1 = *(const float4*)(src + kb + 4);
      bf16x8 u;
      u[0] = (short)f32_to_bf16(v0.x); u[1] = (short)f32_to_bf16(v0.y);
      u[2] = (short)f32_to_bf16(v0.z); u[3] = (short)f32_to_bf16(v0.w);
      u[4] = (short)f32_to_bf16(v1.x); u[5] = (short)f32_to_bf16(v1.y);
      u[6] = (short)f32_to_bf16(v1.z); u[7] = (short)f32_to_bf16(v1.w);
      *(bf16x8*)(&Xs[(p * 64 + srow) * LDSTRIDE + sk0]) = u;
    }
#pragma unroll
    for (int p = 0; p < 2; ++p) {  // stage W rows (cols of output)
      const float* src = p ? bRow1 : bRow0;
      float4 v0 = *(const float4*)(src + kb);
      float4 v1 = *(const float4*)(src + kb + 4);
      bf16x8 u;
      u[0] = (short)f32_to_bf16(v0.x); u[1] = (short)f32_to_bf16(v0.y);
      u[2] = (short)f32_to_bf16(v0.z); u[3] = (short)f32_to_bf16(v0.w);
      u[4] = (short)f32_to_bf16(v1.x); u[5] = (short)f32_to_bf16(v1.y);
      u[6] = (short)f32_to_bf16(v1.z); u[7] = (short)f32_to_bf16(v1.w);
      *(bf16x8*)(&Ws[(p * 64 + srow) * LDSTRIDE + sk0]) = u;
    }
    __syncthreads();

    const int r16 = lane & 15;
    const int qk  = (lane >> 4) << 3;
    bf16x8 wf[2], xf[8];
#pragma unroll
    for (int g = 0; g < 2; ++g)
      wf[g] = *(const bf16x8*)(&Ws[(wid * 32 + g * 16 + r16) * LDSTRIDE + qk]);
#pragma unroll
    for (int g = 0; g < 8; ++g)
      xf[g] = *(const bf16x8*)(&Xs[(g * 16 + r16) * LDSTRIDE + qk]);
#pragma unroll
    for (int ng = 0; ng < 2; ++ng)
#pragma unroll
      for (int ag = 0; ag < 8; ++ag)
        acc[ng][ag] = __builtin_amdgcn_mfma_f32_16x16x32_bf16(
            wf[ng], xf[ag], acc[ng][ag], 0, 0, 0);
    __syncthreads();
  }

#pragma unroll
  for (int ag = 0; ag < 8; ++ag) {
    const int atom = row0 + ag * 16 + c16;
    if (atom >= M) continue;
#pragma unroll
    for (int ng = 0; ng < 2; ++ng) {
      const int n0 = ncol0 + wid * 32 + ng * 16 + quad * 4;
      float v0 = acc[ng][ag][0] + biasv[ng].x;
      float v1 = acc[ng][ag][1] + biasv[ng].y;
      float v2 = acc[ng][ag][2] + biasv[ng].z;
      float v3 = acc[ng][ag][3] + biasv[ng].w;
      if (atom == 0) { v0 = v1 = v2 = v3 = 0.0f; }
      uint2 pk;
      pk.x = (unsigned int)f32_to_bf16(v0) | ((unsigned int)f32_to_bf16(v1) << 16);
      pk.y = (unsigned int)f32_to_bf16(v2) | ((unsigned int)f32_to_bf16(v3) << 16);
      *(uint2*)(h + (size_t)atom * 256 + n0) = pk;
    }
  }
}

// Column-chunked gather with XCD affinity.
// chunk = blockIdx.x & 7 (blocks round-robin over the 8 XCDs -> chunk c's
// random h reads hit XCD c's L2: 50000 x 32 cols x 2B = 3.2 MB < 4 MB L2).
// Block: 64 atoms x 32 cols. Stage 64x16 src indices in LDS (coalesced
// a_from_b int4 + b_from_a gather), then wave w handles atoms w*16..w*16+15:
// lane = (local atom = lane>>2, 8 cols = (lane&3)*8); 17 uint4 loads/atom.
__global__ __launch_bounds__(256, 4) void gin_gather(
    const unsigned short* __restrict__ h, const int* __restrict__ b_from_a,
    const int* __restrict__ a_from_b, float* __restrict__ out, int N) {
  __shared__ int srcs[64 * 17];  // stride 17: conflict-free broadcast reads

  const int chunk = blockIdx.x & 7;
  const int atom0 = (blockIdx.x >> 3) * 64;

  {  // stage indices: thread t covers bonds [atom0*16 + t*4, +4)
    const int t = threadIdx.x;
    int g0 = atom0 * 16 + t * 4;
    int4 bonds;
    if (g0 + 3 < N * 16) {
      bonds = *(const int4*)(a_from_b + g0);
    } else {
      bonds.x = bonds.y = bonds.z = bonds.w = 0;
    }
    const int la = t >> 2;           // local atom 0..63
    const int k0 = (t & 3) * 4;      // neighbor slot 0,4,8,12
    srcs[la * 17 + k0 + 0] = b_from_a[bonds.x];
    srcs[la * 17 + k0 + 1] = b_from_a[bonds.y];
    srcs[la * 17 + k0 + 2] = b_from_a[bonds.z];
    srcs[la * 17 + k0 + 3] = b_from_a[bonds.w];
  }
  __syncthreads();

  const int wid  = threadIdx.x >> 6;
  const int lane = threadIdx.x & 63;
  const int la   = wid * 16 + (lane >> 2);      // local atom 0..63
  const int atom = atom0 + la;
  if (atom >= N) return;

  const int col = chunk * 32 + (lane & 3) * 8;  // 8 cols per lane
  const unsigned short* hp = h + col;

  int s[16];
#pragma unroll
  for (int k = 0; k < 16; ++k) s[k] = srcs[la * 17 + k];

  uint4 v = *(const uint4*)(hp + (size_t)atom * 256);  // self
  float a0 = bf16lo_to_f32(v.x), a1 = bf16hi_to_f32(v.x);
  float a2 = bf16lo_to_f32(v.y), a3 = bf16hi_to_f32(v.y);
  float a4 = bf16lo_to_f32(v.z), a5 = bf16hi_to_f32(v.z);
  float a6 = bf16lo_to_f32(v.w), a7 = bf16hi_to_f32(v.w);
#pragma unroll
  for (int k = 0; k < 16; ++k) {
    uint4 w = *(const uint4*)(hp + (size_t)s[k] * 256);
    a0 += bf16lo_to_f32(w.x); a1 += bf16hi_to_f32(w.x);
    a2 += bf16lo_to_f32(w.y); a3 += bf16hi_to_f32(w.y);
    a4 += bf16lo_to_f32(w.z); a5 += bf16hi_to_f32(w.z);
    a6 += bf16lo_to_f32(w.w); a7 += bf16hi_to_f32(w.w);
  }

  float* op = out + (size_t)atom * 256 + col;
  float4 r0, r1;
  r0.x = fmaxf(a0, 0.0f); r0.y = fmaxf(a1, 0.0f);
  r0.z = fmaxf(a2, 0.0f); r0.w = fmaxf(a3, 0.0f);
  r1.x = fmaxf(a4, 0.0f); r1.y = fmaxf(a5, 0.0f);
  r1.z = fmaxf(a6, 0.0f); r1.w = fmaxf(a7, 0.0f);
  *(float4*)(op)     = r0;
  *(float4*)(op + 4) = r1;
}

extern "C" void kernel_launch(void* const* d_in, const int* in_sizes, int n_in,
                              void* d_out, int out_size, void* d_ws, size_t ws_size,
                              hipStream_t stream) {
  const float* x        = (const float*)d_in[0];
  const float* W        = (const float*)d_in[1];
  const float* b        = (const float*)d_in[2];
  const int*   b_from_a = (const int*)d_in[3];
  const int*   a_from_b = (const int*)d_in[4];
  float*       out      = (float*)d_out;
  const int M = in_sizes[0] / 256;  // 50000 atoms

  unsigned short* h = (unsigned short*)d_ws;  // bf16 h, 25.6 MB

  dim3 ggrid((M + 127) / 128, 2);
  gin_gemm<<<ggrid, 256, 0, stream>>>(x, W, b, h, M);
  const int ablocks = (M + 63) / 64;
  gin_gather<<<ablocks * 8, 256, 0, stream>>>(h, b_from_a, a_from_b, out, M);
}

// Round 6
// 195.265 us; speedup vs baseline: 1.1886x; 1.1886x over previous
//
#include <hip/hip_runtime.h>

typedef short bf16x8 __attribute__((ext_vector_type(8)));
typedef float f32x4  __attribute__((ext_vector_type(4)));
typedef unsigned int u32x4 __attribute__((ext_vector_type(4)));

__device__ __forceinline__ unsigned short f32_to_bf16(float f) {
  union { float f; unsigned int u; } v; v.f = f;
  unsigned int u = v.u;
  u += 0x7fffu + ((u >> 16) & 1u);   // round-to-nearest-even
  return (unsigned short)(u >> 16);
}
__device__ __forceinline__ float bf16lo_to_f32(unsigned int u) {
  union { unsigned int u; float f; } v; v.u = u << 16; return v.f;
}
__device__ __forceinline__ float bf16hi_to_f32(unsigned int u) {
  union { unsigned int u; float f; } v; v.u = u & 0xffff0000u; return v.f;
}

// LDS row stride 40 ushorts (80 B = 20 banks): fragment rows land 20 banks
// apart -> worst 2-way aliasing (free per m136); 80B keeps 16B alignment.
#define LDSTRIDE 40

// h = x @ W.T + b, h[0,:]=0, stored bf16.
// Block: 64 atoms x 256 cols (x read exactly once); 4 waves, wave w owns
// cols [w*64, w*64+64). MFMA operands swapped (A=W, B=x) so D row field =
// output col -> lane holds 4 consecutive cols of one atom -> 8B packed store.
// x loads NONTEMPORAL: x is read once; keep it out of L2 so h (written here,
// random-read by gin_gather next) stays resident.
__global__ __launch_bounds__(256, 2) void gin_gemm(
    const float* __restrict__ x, const float* __restrict__ W,
    const float* __restrict__ bias, unsigned short* __restrict__ h, int M) {
  __shared__ __align__(16) unsigned short Xs[64 * LDSTRIDE];    //  5 KB
  __shared__ __align__(16) unsigned short Ws[256 * LDSTRIDE];   // 20 KB

  const int tid  = threadIdx.x;
  const int wid  = tid >> 6;
  const int lane = tid & 63;
  const int row0 = blockIdx.x * 64;

  f32x4 acc[4][4] = {};  // [ng (col group)][ag (atom group)]

  const int srow = tid >> 2;          // 0..63
  const int sk0  = (tid & 3) << 3;    // 0,8,16,24
  int agrow = row0 + srow;
  if (agrow >= M) agrow = M - 1;      // clamp; stores guarded in epilogue
  const float* aRow = x + (size_t)agrow * 256 + sk0;
  const float* bRow = W + (size_t)srow * 256 + sk0;

  const int quad = lane >> 4;
  const int c16  = lane & 15;
  float4 biasv[4];
#pragma unroll
  for (int ng = 0; ng < 4; ++ng)
    biasv[ng] = *(const float4*)(bias + wid * 64 + ng * 16 + quad * 4);

  for (int kt = 0; kt < 8; ++kt) {
    const int kb = kt * 32;
    {  // stage x: 64x32 f32 -> bf16, nontemporal (single use)
      f32x4 v0 = __builtin_nontemporal_load((const f32x4*)(aRow + kb));
      f32x4 v1 = __builtin_nontemporal_load((const f32x4*)(aRow + kb + 4));
      bf16x8 u;
      u[0] = (short)f32_to_bf16(v0[0]); u[1] = (short)f32_to_bf16(v0[1]);
      u[2] = (short)f32_to_bf16(v0[2]); u[3] = (short)f32_to_bf16(v0[3]);
      u[4] = (short)f32_to_bf16(v1[0]); u[5] = (short)f32_to_bf16(v1[1]);
      u[6] = (short)f32_to_bf16(v1[2]); u[7] = (short)f32_to_bf16(v1[3]);
      *(bf16x8*)(&Xs[srow * LDSTRIDE + sk0]) = u;
    }
#pragma unroll
    for (int j = 0; j < 4; ++j) {  // stage W: 256x32 (reused -> cached)
      const float* p = bRow + (size_t)(j * 64) * 256 + kb;
      float4 v0 = *(const float4*)p;
      float4 v1 = *(const float4*)(p + 4);
      bf16x8 u;
      u[0] = (short)f32_to_bf16(v0.x); u[1] = (short)f32_to_bf16(v0.y);
      u[2] = (short)f32_to_bf16(v0.z); u[3] = (short)f32_to_bf16(v0.w);
      u[4] = (short)f32_to_bf16(v1.x); u[5] = (short)f32_to_bf16(v1.y);
      u[6] = (short)f32_to_bf16(v1.z); u[7] = (short)f32_to_bf16(v1.w);
      *(bf16x8*)(&Ws[(j * 64 + srow) * LDSTRIDE + sk0]) = u;
    }
    __syncthreads();

    const int r16 = lane & 15;
    const int qk  = (lane >> 4) << 3;
    bf16x8 wf[4], xf[4];
#pragma unroll
    for (int g = 0; g < 4; ++g)
      wf[g] = *(const bf16x8*)(&Ws[(wid * 64 + g * 16 + r16) * LDSTRIDE + qk]);
#pragma unroll
    for (int g = 0; g < 4; ++g)
      xf[g] = *(const bf16x8*)(&Xs[(g * 16 + r16) * LDSTRIDE + qk]);
#pragma unroll
    for (int ng = 0; ng < 4; ++ng)
#pragma unroll
      for (int ag = 0; ag < 4; ++ag)
        acc[ng][ag] = __builtin_amdgcn_mfma_f32_16x16x32_bf16(
            wf[ng], xf[ag], acc[ng][ag], 0, 0, 0);
    __syncthreads();
  }

  // epilogue: D col field = atom = row0+ag*16+c16, row field = out col
#pragma unroll
  for (int ag = 0; ag < 4; ++ag) {
    const int atom = row0 + ag * 16 + c16;
    if (atom >= M) continue;
#pragma unroll
    for (int ng = 0; ng < 4; ++ng) {
      const int n0 = wid * 64 + ng * 16 + quad * 4;
      float v0 = acc[ng][ag][0] + biasv[ng].x;
      float v1 = acc[ng][ag][1] + biasv[ng].y;
      float v2 = acc[ng][ag][2] + biasv[ng].z;
      float v3 = acc[ng][ag][3] + biasv[ng].w;
      if (atom == 0) { v0 = v1 = v2 = v3 = 0.0f; }
      uint2 pk;
      pk.x = (unsigned int)f32_to_bf16(v0) | ((unsigned int)f32_to_bf16(v1) << 16);
      pk.y = (unsigned int)f32_to_bf16(v2) | ((unsigned int)f32_to_bf16(v3) << 16);
      *(uint2*)(h + (size_t)atom * 256 + n0) = pk;  // cached: gather wants h in L2
    }
  }
}

// out[i] = relu(h[i] + sum_k h[b_from_a[a_from_b[i,k]]]); one wave per atom.
// Half-waves cover a full 512B row per load (full-line granules).
// out stores NONTEMPORAL: out is write-once, never re-read -- keep the 51 MB
// write stream from evicting h (25.6 MB, random-read) out of L2.
__global__ __launch_bounds__(256, 4) void gin_gather(
    const unsigned short* __restrict__ h, const int* __restrict__ b_from_a,
    const int* __restrict__ a_from_b, float* __restrict__ out, int N) {
  const int wid  = threadIdx.x >> 6;
  const int lane = threadIdx.x & 63;
  const int i = blockIdx.x * 4 + wid;
  if (i >= N) return;

  const int half = lane >> 5;      // 0: neighbors 0-7 (+self), 1: neighbors 8-15
  const int hl   = lane & 31;
  const int c0   = hl << 3;        // 8 cols per lane

  int src = 0;
  if (lane < 16)
    src = b_from_a[__builtin_nontemporal_load(a_from_b + i * 16 + lane)];

  const unsigned short* hp = h + c0;

  // self row: both halves load (L1-coalesced), only half 0 accumulates it
  float a0, a1, a2, a3, a4, a5, a6, a7;
  {
    uint4 v = *(const uint4*)(hp + (size_t)i * 256);
    const float selfw = half ? 0.0f : 1.0f;
    a0 = selfw * bf16lo_to_f32(v.x); a1 = selfw * bf16hi_to_f32(v.x);
    a2 = selfw * bf16lo_to_f32(v.y); a3 = selfw * bf16hi_to_f32(v.y);
    a4 = selfw * bf16lo_to_f32(v.z); a5 = selfw * bf16hi_to_f32(v.z);
    a6 = selfw * bf16lo_to_f32(v.w); a7 = selfw * bf16hi_to_f32(v.w);
  }
#pragma unroll
  for (int k = 0; k < 8; ++k) {
    int s = __shfl(src, half * 8 + k, 64);
    uint4 v = *(const uint4*)(hp + (size_t)s * 256);
    a0 += bf16lo_to_f32(v.x); a1 += bf16hi_to_f32(v.x);
    a2 += bf16lo_to_f32(v.y); a3 += bf16hi_to_f32(v.y);
    a4 += bf16lo_to_f32(v.z); a5 += bf16hi_to_f32(v.z);
    a6 += bf16lo_to_f32(v.w); a7 += bf16hi_to_f32(v.w);
  }
  // cross-half combine
  a0 += __shfl_xor(a0, 32, 64); a1 += __shfl_xor(a1, 32, 64);
  a2 += __shfl_xor(a2, 32, 64); a3 += __shfl_xor(a3, 32, 64);
  a4 += __shfl_xor(a4, 32, 64); a5 += __shfl_xor(a5, 32, 64);
  a6 += __shfl_xor(a6, 32, 64); a7 += __shfl_xor(a7, 32, 64);

  f32x4 r;
  if (half == 0) {
    r[0] = fmaxf(a0, 0.0f); r[1] = fmaxf(a1, 0.0f);
    r[2] = fmaxf(a2, 0.0f); r[3] = fmaxf(a3, 0.0f);
  } else {
    r[0] = fmaxf(a4, 0.0f); r[1] = fmaxf(a5, 0.0f);
    r[2] = fmaxf(a6, 0.0f); r[3] = fmaxf(a7, 0.0f);
  }
  __builtin_nontemporal_store(r, (f32x4*)(out + (size_t)i * 256 + c0 + half * 4));
}

extern "C" void kernel_launch(void* const* d_in, const int* in_sizes, int n_in,
                              void* d_out, int out_size, void* d_ws, size_t ws_size,
                              hipStream_t stream) {
  const float* x        = (const float*)d_in[0];
  const float* W        = (const float*)d_in[1];
  const float* b        = (const float*)d_in[2];
  const int*   b_from_a = (const int*)d_in[3];
  const int*   a_from_b = (const int*)d_in[4];
  float*       out      = (float*)d_out;
  const int M = in_sizes[0] / 256;  // 50000 atoms

  unsigned short* h = (unsigned short*)d_ws;  // bf16 h, 25.6 MB

  gin_gemm<<<(M + 63) / 64, 256, 0, stream>>>(x, W, b, h, M);
  gin_gather<<<(M + 3) / 4, 256, 0, stream>>>(h, b_from_a, a_from_b, out, M);
}